// Round 1
// baseline (748.978 us; speedup 1.0000x reference)
//
#include <hip/hip_runtime.h>

// ---------------------------------------------------------------------------
// GCN: 4 layers of  h' = A_hat_norm (h @ W) + b   on fixed graph, fp32.
// deg[i] = in_degree(i) + 1 (self loop), dinv = 1/sqrt(deg),
// g = (h@W) * dinv[row]  (GEMM epilogue), then per-dst:
//   h'[dst] = dinv[dst] * ( g[dst] + sum_{src in N(dst)} g[src] ) + b
// R2: gemm spill fixed (unroll 1 + manual pipeline).
// R3: CSR fill via binned counting sort (L2-merged scatters).
// R4: per-node degree/scan/fill in LDS per 256-node bin. (784us, best)
// R5-R8: feature-chunked G + XCD pinning experiments -- chunk residency
// never held under long-lived blocks (FETCH bounced back to 257MB) and
// latency suffered; REVERTED to R4 structure.
// R9: R4 + agg gather loop unrolled to 8 independent chains. (748us)
// R10: agg gathers widened to dwordx4 (16 lanes/row, 4 rows per load
// instruction, 4 chains -> 16 rows in flight/wave vs 8). Theory: agg is
// gather-LATENCY-bound (VALUBusy 27%, occupancy 77%, fetch 362MB at only
// 3.65TB/s); 2x MLP at 1/4 the instruction count should push toward the
// L2-miss BW ceiling. Cross-group combine: 2x shfl_xor(16,32) epilogue.
// ---------------------------------------------------------------------------

#define FEAT 128
#define EMB 64
#define BINSHIFT 8
#define BINSIZE 256
#define NBIN 391          // ceil(100000/256)
#define CHUNK 8192

// ---------------- CSR build ----------------

__global__ void zero_k(int* __restrict__ p, int n) {
    int i = blockIdx.x * blockDim.x + threadIdx.x;
    if (i < n) p[i] = 0;
}

// Pass A: per-bin edge counts. LDS histogram per chunk.
__global__ __launch_bounds__(256) void bin_count_k(
    const int* __restrict__ dst, int* __restrict__ bincnt, int E) {
    __shared__ int hist[NBIN];
    int t = threadIdx.x;
    int base = blockIdx.x * CHUNK;
    int end = min(base + CHUNK, E);
    for (int i = t; i < NBIN; i += 256) hist[i] = 0;
    __syncthreads();
    for (int e = base + t; e < end; e += 256)
        atomicAdd(&hist[dst[e] >> BINSHIFT], 1);
    __syncthreads();
    for (int b = t; b < NBIN; b += 256) {
        int c = hist[b];
        if (c > 0) atomicAdd(&bincnt[b], c);
    }
}

// exclusive scan of bin counts (NBIN <= 512), writes binptr + bincur.
__global__ void binscan_k(const int* __restrict__ bincnt, int* __restrict__ binptr,
                          int* __restrict__ bincur, int nbin, int E) {
    __shared__ int s[512];
    int t = threadIdx.x;
    int v = (t < nbin) ? bincnt[t] : 0;
    s[t] = v;
    __syncthreads();
    for (int off = 1; off < 512; off <<= 1) {
        int tv = (t >= off) ? s[t - off] : 0;
        __syncthreads();
        s[t] += tv;
        __syncthreads();
    }
    if (t < nbin) {
        int excl = s[t] - v;
        binptr[t] = excl;
        bincur[t] = excl;
    }
    if (t == 0) binptr[nbin] = E;
}

// Pass B: scatter edges into dst-range bins. One block per 8192-edge chunk.
// Output word: src | (dst&255)<<24  (src < 2^17 fits in 24 bits).
__global__ __launch_bounds__(256) void bin_edges_k(
    const int* __restrict__ src, const int* __restrict__ dst,
    int* __restrict__ bincur, int* __restrict__ ebuf, int E) {
    __shared__ int hist[NBIN];
    __shared__ int lcur[NBIN];
    int t = threadIdx.x;
    int base = blockIdx.x * CHUNK;
    int end = min(base + CHUNK, E);
    for (int i = t; i < NBIN; i += 256) hist[i] = 0;
    __syncthreads();
    for (int e = base + t; e < end; e += 256)
        atomicAdd(&hist[dst[e] >> BINSHIFT], 1);
    __syncthreads();
    for (int b = t; b < NBIN; b += 256) {
        int c = hist[b];
        lcur[b] = (c > 0) ? atomicAdd(&bincur[b], c) : 0;
    }
    __syncthreads();
    for (int e = base + t; e < end; e += 256) {
        int d = dst[e];
        int bin = d >> BINSHIFT;
        int r = atomicAdd(&lcur[bin], 1);
        ebuf[r] = src[e] | ((d & (BINSIZE - 1)) << 24);
    }
}

// Pass C: one block per bin. LDS degree count -> LDS scan -> rowptr/dinv
// writes -> col scatter with LDS cursors. No global per-node atomics.
__global__ __launch_bounds__(256) void build_csr_k(
    const int* __restrict__ ebuf, const int* __restrict__ binptr,
    int* __restrict__ rowptr, float* __restrict__ dinv,
    int* __restrict__ col, int N, int E, int nbin) {
    __shared__ int lcnt[BINSIZE];
    __shared__ int lscan[BINSIZE];
    __shared__ int lcur[BINSIZE];
    int b = blockIdx.x;
    int t = threadIdx.x;
    int n0 = b << BINSHIFT;
    int e0 = binptr[b];
    int e1 = binptr[b + 1];

    lcnt[t] = 0;
    __syncthreads();
    for (int i = e0 + t; i < e1; i += 256)
        atomicAdd(&lcnt[((unsigned)ebuf[i]) >> 24], 1);
    __syncthreads();

    int v = lcnt[t];
    lscan[t] = v;
    __syncthreads();
    for (int off = 1; off < 256; off <<= 1) {
        int tv = (t >= off) ? lscan[t - off] : 0;
        __syncthreads();
        lscan[t] += tv;
        __syncthreads();
    }
    int excl = e0 + lscan[t] - v;
    lcur[t] = excl;
    if (n0 + t < N) {
        rowptr[n0 + t] = excl;
        dinv[n0 + t] = 1.0f / sqrtf((float)(v + 1));
    }
    if (b == nbin - 1 && t == 0) rowptr[N] = E;
    __syncthreads();

    for (int i = e0 + t; i < e1; i += 256) {
        int w = ebuf[i];
        int dl = ((unsigned)w) >> 24;
        int p = atomicAdd(&lcur[dl], 1);
        col[p] = w & 0xFFFFFF;
    }
}

// ---------------- GEMM + dinv row-scale:  G = (H @ W) * dinv[row] ----------------
// Block: 256 threads -> 64 rows x 64 cols, each thread 4x4 outputs.
// Manual 1-deep pipeline on the A loads; unroll 1 keeps VGPR < 128.
template <int K>
__global__ __launch_bounds__(256, 4) void gemm_scale_k(
    const float* __restrict__ H, const float* __restrict__ W,
    const float* __restrict__ dinv, float* __restrict__ G, int N) {
    __shared__ float Ws[K * EMB];
    int t = threadIdx.x;
    for (int i = t * 4; i < K * EMB; i += 1024) {
        *(float4*)(Ws + i) = *(const float4*)(W + i);
    }
    __syncthreads();

    int tc = t & 15;   // col group -> 4 cols
    int tr = t >> 4;   // row group -> 4 rows
    int j0 = tc * 4;
    int r0 = blockIdx.x * 64 + tr * 4;
    if (r0 >= N) return;

    const float* hp[4];
#pragma unroll
    for (int i = 0; i < 4; i++) {
        int r = (r0 + i < N) ? (r0 + i) : (N - 1);
        hp[i] = H + (size_t)r * K;
    }

    float acc[4][4] = {{0.f}};
    float4 a[4], an[4];
#pragma unroll
    for (int i = 0; i < 4; i++) a[i] = *(const float4*)(hp[i]);

#pragma unroll 1
    for (int k = 0; k < K; k += 4) {
        if (k + 4 < K) {
#pragma unroll
            for (int i = 0; i < 4; i++) an[i] = *(const float4*)(hp[i] + k + 4);
        }
#pragma unroll
        for (int kk = 0; kk < 4; kk++) {
            float4 wv = *(const float4*)(Ws + (k + kk) * EMB + j0);
#pragma unroll
            for (int i = 0; i < 4; i++) {
                float av = (kk == 0) ? a[i].x : (kk == 1) ? a[i].y : (kk == 2) ? a[i].z : a[i].w;
                acc[i][0] = fmaf(av, wv.x, acc[i][0]);
                acc[i][1] = fmaf(av, wv.y, acc[i][1]);
                acc[i][2] = fmaf(av, wv.z, acc[i][2]);
                acc[i][3] = fmaf(av, wv.w, acc[i][3]);
            }
        }
#pragma unroll
        for (int i = 0; i < 4; i++) a[i] = an[i];
    }

#pragma unroll
    for (int i = 0; i < 4; i++) {
        if (r0 + i < N) {
            float s = dinv[r0 + i];
            float4 o = make_float4(acc[i][0] * s, acc[i][1] * s, acc[i][2] * s, acc[i][3] * s);
            *(float4*)(G + (size_t)(r0 + i) * EMB + j0) = o;
        }
    }
}

// ---------------- Aggregation: one wave per node ----------------
// R10: dwordx4 gathers. 16 lanes cover one 256B G-row (float4/lane); the
// wave's 4 sixteen-lane groups each handle every 4th edge -> one load
// instruction fetches 4 rows. 4 unrolled chains -> 16 rows outstanding per
// wave (vs 8 dword rows in R9) at ~1/4 the instruction count. col indices
// are fetched per-lane (broadcast within group) and prefetched one
// iteration ahead so the col->G dependency pipelines. Self-loop folds into
// group 0. Epilogue: shfl_xor(16) + shfl_xor(32) combine the 4 groups;
// every lane ends with the full sum for its feature quad (lane&15).

__device__ __forceinline__ float4 agg_node4(const float* __restrict__ G,
                                            const int* __restrict__ col,
                                            int s, int e, int node,
                                            int grp, int f4) {
    const float* Gf = G + (size_t)f4 * 4;   // lane's 16B slice within a row
    float4 a0 = make_float4(0.f, 0.f, 0.f, 0.f);
    float4 a1 = a0, a2 = a0, a3 = a0;
    if (grp == 0) a0 = *(const float4*)(Gf + (size_t)node * EMB);  // self loop

    int i = s;
    if (i + 16 <= e) {
        int c0 = col[i + grp];
        int c1 = col[i + 4 + grp];
        int c2 = col[i + 8 + grp];
        int c3 = col[i + 12 + grp];
        while (true) {
            float4 g0 = *(const float4*)(Gf + (size_t)c0 * EMB);
            float4 g1 = *(const float4*)(Gf + (size_t)c1 * EMB);
            float4 g2 = *(const float4*)(Gf + (size_t)c2 * EMB);
            float4 g3 = *(const float4*)(Gf + (size_t)c3 * EMB);
            i += 16;
            bool more = (i + 16 <= e);
            if (more) {                       // prefetch next iter's cols
                c0 = col[i + grp];
                c1 = col[i + 4 + grp];
                c2 = col[i + 8 + grp];
                c3 = col[i + 12 + grp];
            }
            a0.x += g0.x; a0.y += g0.y; a0.z += g0.z; a0.w += g0.w;
            a1.x += g1.x; a1.y += g1.y; a1.z += g1.z; a1.w += g1.w;
            a2.x += g2.x; a2.y += g2.y; a2.z += g2.z; a2.w += g2.w;
            a3.x += g3.x; a3.y += g3.y; a3.z += g3.z; a3.w += g3.w;
            if (!more) break;
        }
    }
    // 4..15 leftover edges, 4 at a time (one row per group)
    for (; i + 4 <= e; i += 4) {
        int c = col[i + grp];
        float4 g = *(const float4*)(Gf + (size_t)c * EMB);
        a1.x += g.x; a1.y += g.y; a1.z += g.z; a1.w += g.w;
    }
    // final 0..3 edges: only the first (e-i) groups load
    if (grp < e - i) {
        int c = col[i + grp];
        float4 g = *(const float4*)(Gf + (size_t)c * EMB);
        a2.x += g.x; a2.y += g.y; a2.z += g.z; a2.w += g.w;
    }

    float4 r;
    r.x = (a0.x + a1.x) + (a2.x + a3.x);
    r.y = (a0.y + a1.y) + (a2.y + a3.y);
    r.z = (a0.z + a1.z) + (a2.z + a3.z);
    r.w = (a0.w + a1.w) + (a2.w + a3.w);
    // combine the 4 sixteen-lane groups
    r.x += __shfl_xor(r.x, 16, 64);
    r.y += __shfl_xor(r.y, 16, 64);
    r.z += __shfl_xor(r.z, 16, 64);
    r.w += __shfl_xor(r.w, 16, 64);
    r.x += __shfl_xor(r.x, 32, 64);
    r.y += __shfl_xor(r.y, 32, 64);
    r.z += __shfl_xor(r.z, 32, 64);
    r.w += __shfl_xor(r.w, 32, 64);
    return r;   // all 64 lanes: full sum for features [4*f4 .. 4*f4+3]
}

__global__ __launch_bounds__(256) void agg_k(
    const float* __restrict__ G, const float* __restrict__ dinv,
    const int* __restrict__ rowptr, const int* __restrict__ col,
    const float* __restrict__ bias, float* __restrict__ Hout, int N) {
    int gw = (blockIdx.x * 256 + threadIdx.x) >> 6;
    int lane = threadIdx.x & 63;
    if (gw >= N) return;
    int grp = lane >> 4;
    int f4 = lane & 15;
    int s = rowptr[gw], e = rowptr[gw + 1];
    float4 r = agg_node4(G, col, s, e, gw, grp, f4);
    float d = dinv[gw];
    float4 bv = *(const float4*)(bias + f4 * 4);
    float4 val = make_float4(r.x * d + bv.x, r.y * d + bv.y,
                             r.z * d + bv.z, r.w * d + bv.w);
    if (grp == 0)
        *(float4*)(Hout + (size_t)gw * EMB + f4 * 4) = val;
}

// Final layer: also project y @ Wout + bout into Out.
__global__ __launch_bounds__(256) void agg_final_k(
    const float* __restrict__ G, const float* __restrict__ dinv,
    const int* __restrict__ rowptr, const int* __restrict__ col,
    const float* __restrict__ bias, const float* __restrict__ Wout,
    const float* __restrict__ bout, float* __restrict__ Y,
    float* __restrict__ Out, int N) {
    int gw = (blockIdx.x * 256 + threadIdx.x) >> 6;
    int lane = threadIdx.x & 63;
    if (gw >= N) return;
    int grp = lane >> 4;
    int f4 = lane & 15;
    int s = rowptr[gw], e = rowptr[gw + 1];
    float4 r = agg_node4(G, col, s, e, gw, grp, f4);
    float d = dinv[gw];
    float4 bv = *(const float4*)(bias + f4 * 4);
    float4 val = make_float4(r.x * d + bv.x, r.y * d + bv.y,
                             r.z * d + bv.z, r.w * d + bv.w);
    if (grp == 0)
        *(float4*)(Y + (size_t)gw * EMB + f4 * 4) = val;
    // output projection: every lane holds the same val for its f4 slice;
    // lanes 0..15 together cover all 64 features -> reduce within group.
    float4 wv = *(const float4*)(Wout + f4 * 4);
    float p = val.x * wv.x + val.y * wv.y + val.z * wv.z + val.w * wv.w;
    p += __shfl_xor(p, 8, 64);
    p += __shfl_xor(p, 4, 64);
    p += __shfl_xor(p, 2, 64);
    p += __shfl_xor(p, 1, 64);
    if (lane == 0) Out[gw] = p + bout[0];
}

// ---------------- launch ----------------

extern "C" void kernel_launch(void* const* d_in, const int* in_sizes, int n_in,
                              void* d_out, int out_size, void* d_ws, size_t ws_size,
                              hipStream_t stream) {
    const float* x    = (const float*)d_in[0];
    const int*   ei   = (const int*)d_in[1];
    const float* W0   = (const float*)d_in[3];
    const float* b0   = (const float*)d_in[4];
    const float* W1   = (const float*)d_in[5];
    const float* b1   = (const float*)d_in[6];
    const float* W2   = (const float*)d_in[7];
    const float* b2   = (const float*)d_in[8];
    const float* W3   = (const float*)d_in[9];
    const float* b3   = (const float*)d_in[10];
    const float* Wout = (const float*)d_in[11];
    const float* bout = (const float*)d_in[12];

    const int N = in_sizes[0] / FEAT;      // 100000
    const int E = in_sizes[1] / 2;         // 3200000
    const int* srcp = ei;                  // edge_index[0]
    const int* dstp = ei + E;              // edge_index[1]
    const int nbin = (N + BINSIZE - 1) / BINSIZE;   // 391

    // workspace layout (regions padded to 64 elems for float4 alignment)
    const int NP = ((N + 64) + 63) / 64 * 64;   // holds N+1
    float* dinv  = (float*)d_ws;
    int* rowptr  = (int*)(dinv + NP);
    int* bincnt  = rowptr + NP;
    int* binptr  = bincnt + 1024;
    int* bincur  = binptr + 1024;
    int* col     = bincur + 1024;
    float* bufA  = (float*)(col + ((E + 63) / 64) * 64);
    int* ebuf    = (int*)bufA;            // aliased: ebuf dead before first gemm

    float* Out = (float*)d_out;
    float* Y   = Out + N;                 // reuse y-region of d_out as ping-pong buffer

    const int gemm_blocks = (N + 63) / 64;
    const int agg_blocks  = (N + 3) / 4;
    const int nchunk = (E + CHUNK - 1) / CHUNK;

    // --- CSR build ---
    zero_k<<<1, 1024, 0, stream>>>(bincnt, 1024);
    bin_count_k<<<nchunk, 256, 0, stream>>>(dstp, bincnt, E);
    binscan_k<<<1, 512, 0, stream>>>(bincnt, binptr, bincur, nbin, E);
    bin_edges_k<<<nchunk, 256, 0, stream>>>(srcp, dstp, bincur, ebuf, E);
    build_csr_k<<<nbin, 256, 0, stream>>>(ebuf, binptr, rowptr, dinv, col, N, E, nbin);

    // --- layer 0 (K=128) ---
    gemm_scale_k<FEAT><<<gemm_blocks, 256, 0, stream>>>(x, W0, dinv, bufA, N);
    agg_k<<<agg_blocks, 256, 0, stream>>>(bufA, dinv, rowptr, col, b0, Y, N);
    // --- layer 1 ---
    gemm_scale_k<EMB><<<gemm_blocks, 256, 0, stream>>>(Y, W1, dinv, bufA, N);
    agg_k<<<agg_blocks, 256, 0, stream>>>(bufA, dinv, rowptr, col, b1, Y, N);
    // --- layer 2 ---
    gemm_scale_k<EMB><<<gemm_blocks, 256, 0, stream>>>(Y, W2, dinv, bufA, N);
    agg_k<<<agg_blocks, 256, 0, stream>>>(bufA, dinv, rowptr, col, b2, Y, N);
    // --- layer 3 + output projection ---
    gemm_scale_k<EMB><<<gemm_blocks, 256, 0, stream>>>(Y, W3, dinv, bufA, N);
    agg_final_k<<<agg_blocks, 256, 0, stream>>>(bufA, dinv, rowptr, col, b3, Wout, bout,
                                                Y, Out, N);
}

// Round 2
// 587.027 us; speedup vs baseline: 1.2759x; 1.2759x over previous
//
#include <hip/hip_runtime.h>
#include <hip/hip_fp16.h>

// ---------------------------------------------------------------------------
// GCN: 4 layers of  h' = A_hat_norm (h @ W) + b   on fixed graph, fp32.
// deg[i] = in_degree(i) + 1 (self loop), dinv = 1/sqrt(deg),
// g = (h@W) * dinv[row]  (GEMM epilogue), then per-dst:
//   h'[dst] = dinv[dst] * ( g[dst] + sum_{src in N(dst)} g[src] ) + b
// R2: gemm spill fixed (unroll 1 + manual pipeline).
// R3: CSR fill via binned counting sort (L2-merged scatters).
// R4: per-node degree/scan/fill in LDS per 256-node bin. (784us, best)
// R5-R8: feature-chunked G + XCD pinning: REVERTED (residency never held).
// R9: agg gather unrolled to 8 chains. (748us)
// R10: dwordx4 gathers, 16 rows in flight/wave. (749us, +2% per-dispatch only)
//   -> MLP is NOT the limiter. agg is BW-bound on the L2-miss path:
//      demand 845MB -> FETCH 362MB pinned at ~3.7TB/s across R9/R10.
// R11: G stored as fp16 (half the bytes per edge). Rows 256B->128B, demand
//   ~435MB, working set 25.6->12.8MB (L2 hit rate should also rise).
//   Accumulate fp32; Y stays fp32 (one rounding per value per layer).
//   Predicted: FETCH 362->~180MB, agg 107->~60us, total ~550us.
// ---------------------------------------------------------------------------

#define FEAT 128
#define EMB 64
#define BINSHIFT 8
#define BINSIZE 256
#define NBIN 391          // ceil(100000/256)
#define CHUNK 8192

// ---------------- CSR build ----------------

__global__ void zero_k(int* __restrict__ p, int n) {
    int i = blockIdx.x * blockDim.x + threadIdx.x;
    if (i < n) p[i] = 0;
}

// Pass A: per-bin edge counts. LDS histogram per chunk.
__global__ __launch_bounds__(256) void bin_count_k(
    const int* __restrict__ dst, int* __restrict__ bincnt, int E) {
    __shared__ int hist[NBIN];
    int t = threadIdx.x;
    int base = blockIdx.x * CHUNK;
    int end = min(base + CHUNK, E);
    for (int i = t; i < NBIN; i += 256) hist[i] = 0;
    __syncthreads();
    for (int e = base + t; e < end; e += 256)
        atomicAdd(&hist[dst[e] >> BINSHIFT], 1);
    __syncthreads();
    for (int b = t; b < NBIN; b += 256) {
        int c = hist[b];
        if (c > 0) atomicAdd(&bincnt[b], c);
    }
}

// exclusive scan of bin counts (NBIN <= 512), writes binptr + bincur.
__global__ void binscan_k(const int* __restrict__ bincnt, int* __restrict__ binptr,
                          int* __restrict__ bincur, int nbin, int E) {
    __shared__ int s[512];
    int t = threadIdx.x;
    int v = (t < nbin) ? bincnt[t] : 0;
    s[t] = v;
    __syncthreads();
    for (int off = 1; off < 512; off <<= 1) {
        int tv = (t >= off) ? s[t - off] : 0;
        __syncthreads();
        s[t] += tv;
        __syncthreads();
    }
    if (t < nbin) {
        int excl = s[t] - v;
        binptr[t] = excl;
        bincur[t] = excl;
    }
    if (t == 0) binptr[nbin] = E;
}

// Pass B: scatter edges into dst-range bins. One block per 8192-edge chunk.
// Output word: src | (dst&255)<<24  (src < 2^17 fits in 24 bits).
__global__ __launch_bounds__(256) void bin_edges_k(
    const int* __restrict__ src, const int* __restrict__ dst,
    int* __restrict__ bincur, int* __restrict__ ebuf, int E) {
    __shared__ int hist[NBIN];
    __shared__ int lcur[NBIN];
    int t = threadIdx.x;
    int base = blockIdx.x * CHUNK;
    int end = min(base + CHUNK, E);
    for (int i = t; i < NBIN; i += 256) hist[i] = 0;
    __syncthreads();
    for (int e = base + t; e < end; e += 256)
        atomicAdd(&hist[dst[e] >> BINSHIFT], 1);
    __syncthreads();
    for (int b = t; b < NBIN; b += 256) {
        int c = hist[b];
        lcur[b] = (c > 0) ? atomicAdd(&bincur[b], c) : 0;
    }
    __syncthreads();
    for (int e = base + t; e < end; e += 256) {
        int d = dst[e];
        int bin = d >> BINSHIFT;
        int r = atomicAdd(&lcur[bin], 1);
        ebuf[r] = src[e] | ((d & (BINSIZE - 1)) << 24);
    }
}

// Pass C: one block per bin. LDS degree count -> LDS scan -> rowptr/dinv
// writes -> col scatter with LDS cursors. No global per-node atomics.
__global__ __launch_bounds__(256) void build_csr_k(
    const int* __restrict__ ebuf, const int* __restrict__ binptr,
    int* __restrict__ rowptr, float* __restrict__ dinv,
    int* __restrict__ col, int N, int E, int nbin) {
    __shared__ int lcnt[BINSIZE];
    __shared__ int lscan[BINSIZE];
    __shared__ int lcur[BINSIZE];
    int b = blockIdx.x;
    int t = threadIdx.x;
    int n0 = b << BINSHIFT;
    int e0 = binptr[b];
    int e1 = binptr[b + 1];

    lcnt[t] = 0;
    __syncthreads();
    for (int i = e0 + t; i < e1; i += 256)
        atomicAdd(&lcnt[((unsigned)ebuf[i]) >> 24], 1);
    __syncthreads();

    int v = lcnt[t];
    lscan[t] = v;
    __syncthreads();
    for (int off = 1; off < 256; off <<= 1) {
        int tv = (t >= off) ? lscan[t - off] : 0;
        __syncthreads();
        lscan[t] += tv;
        __syncthreads();
    }
    int excl = e0 + lscan[t] - v;
    lcur[t] = excl;
    if (n0 + t < N) {
        rowptr[n0 + t] = excl;
        dinv[n0 + t] = 1.0f / sqrtf((float)(v + 1));
    }
    if (b == nbin - 1 && t == 0) rowptr[N] = E;
    __syncthreads();

    for (int i = e0 + t; i < e1; i += 256) {
        int w = ebuf[i];
        int dl = ((unsigned)w) >> 24;
        int p = atomicAdd(&lcur[dl], 1);
        col[p] = w & 0xFFFFFF;
    }
}

// ---------------- GEMM + dinv row-scale:  G = (H @ W) * dinv[row], fp16 out ----
// Block: 256 threads -> 64 rows x 64 cols, each thread 4x4 outputs.
// Manual 1-deep pipeline on the A loads; unroll 1 keeps VGPR < 128.
template <int K>
__global__ __launch_bounds__(256, 4) void gemm_scale_k(
    const float* __restrict__ H, const float* __restrict__ W,
    const float* __restrict__ dinv, __half* __restrict__ G, int N) {
    __shared__ float Ws[K * EMB];
    int t = threadIdx.x;
    for (int i = t * 4; i < K * EMB; i += 1024) {
        *(float4*)(Ws + i) = *(const float4*)(W + i);
    }
    __syncthreads();

    int tc = t & 15;   // col group -> 4 cols
    int tr = t >> 4;   // row group -> 4 rows
    int j0 = tc * 4;
    int r0 = blockIdx.x * 64 + tr * 4;
    if (r0 >= N) return;

    const float* hp[4];
#pragma unroll
    for (int i = 0; i < 4; i++) {
        int r = (r0 + i < N) ? (r0 + i) : (N - 1);
        hp[i] = H + (size_t)r * K;
    }

    float acc[4][4] = {{0.f}};
    float4 a[4], an[4];
#pragma unroll
    for (int i = 0; i < 4; i++) a[i] = *(const float4*)(hp[i]);

#pragma unroll 1
    for (int k = 0; k < K; k += 4) {
        if (k + 4 < K) {
#pragma unroll
            for (int i = 0; i < 4; i++) an[i] = *(const float4*)(hp[i] + k + 4);
        }
#pragma unroll
        for (int kk = 0; kk < 4; kk++) {
            float4 wv = *(const float4*)(Ws + (k + kk) * EMB + j0);
#pragma unroll
            for (int i = 0; i < 4; i++) {
                float av = (kk == 0) ? a[i].x : (kk == 1) ? a[i].y : (kk == 2) ? a[i].z : a[i].w;
                acc[i][0] = fmaf(av, wv.x, acc[i][0]);
                acc[i][1] = fmaf(av, wv.y, acc[i][1]);
                acc[i][2] = fmaf(av, wv.z, acc[i][2]);
                acc[i][3] = fmaf(av, wv.w, acc[i][3]);
            }
        }
#pragma unroll
        for (int i = 0; i < 4; i++) a[i] = an[i];
    }

#pragma unroll
    for (int i = 0; i < 4; i++) {
        if (r0 + i < N) {
            float s = dinv[r0 + i];
            union { __half2 h2[2]; float2 f2; } o;
            o.h2[0] = __floats2half2_rn(acc[i][0] * s, acc[i][1] * s);
            o.h2[1] = __floats2half2_rn(acc[i][2] * s, acc[i][3] * s);
            *(float2*)(G + (size_t)(r0 + i) * EMB + j0) = o.f2;
        }
    }
}

// ---------------- Aggregation: one wave per node, fp16 G rows ----------------
// 16 lanes cover one 128B fp16 G-row (4 halves = 8B per lane); the wave's 4
// sixteen-lane groups each handle every 4th edge -> one dwordx2 load
// instruction fetches 4 rows. 4 chains -> 16 rows outstanding per wave.
// col indices prefetched one iteration ahead. Accumulate fp32; epilogue
// combines the 4 groups with shfl_xor(16,32).

__device__ __forceinline__ float4 h4_to_f4(float2 raw) {
    union { float2 f2; __half2 h2[2]; } u;
    u.f2 = raw;
    float2 lo = __half22float2(u.h2[0]);
    float2 hi = __half22float2(u.h2[1]);
    return make_float4(lo.x, lo.y, hi.x, hi.y);
}

__device__ __forceinline__ float4 agg_node4(const __half* __restrict__ G,
                                            const int* __restrict__ col,
                                            int s, int e, int node,
                                            int grp, int f4) {
    const __half* Gf = G + (size_t)f4 * 4;   // lane's 8B slice within a row
    float4 a0 = make_float4(0.f, 0.f, 0.f, 0.f);
    float4 a1 = a0, a2 = a0, a3 = a0;
    if (grp == 0) {                           // self loop
        float4 g = h4_to_f4(*(const float2*)(Gf + (size_t)node * EMB));
        a0.x += g.x; a0.y += g.y; a0.z += g.z; a0.w += g.w;
    }

    int i = s;
    if (i + 16 <= e) {
        int c0 = col[i + grp];
        int c1 = col[i + 4 + grp];
        int c2 = col[i + 8 + grp];
        int c3 = col[i + 12 + grp];
        while (true) {
            float2 r0 = *(const float2*)(Gf + (size_t)c0 * EMB);
            float2 r1 = *(const float2*)(Gf + (size_t)c1 * EMB);
            float2 r2 = *(const float2*)(Gf + (size_t)c2 * EMB);
            float2 r3 = *(const float2*)(Gf + (size_t)c3 * EMB);
            i += 16;
            bool more = (i + 16 <= e);
            if (more) {                       // prefetch next iter's cols
                c0 = col[i + grp];
                c1 = col[i + 4 + grp];
                c2 = col[i + 8 + grp];
                c3 = col[i + 12 + grp];
            }
            float4 g0 = h4_to_f4(r0);
            float4 g1 = h4_to_f4(r1);
            float4 g2 = h4_to_f4(r2);
            float4 g3 = h4_to_f4(r3);
            a0.x += g0.x; a0.y += g0.y; a0.z += g0.z; a0.w += g0.w;
            a1.x += g1.x; a1.y += g1.y; a1.z += g1.z; a1.w += g1.w;
            a2.x += g2.x; a2.y += g2.y; a2.z += g2.z; a2.w += g2.w;
            a3.x += g3.x; a3.y += g3.y; a3.z += g3.z; a3.w += g3.w;
            if (!more) break;
        }
    }
    // 4..15 leftover edges, 4 at a time (one row per group)
    for (; i + 4 <= e; i += 4) {
        int c = col[i + grp];
        float4 g = h4_to_f4(*(const float2*)(Gf + (size_t)c * EMB));
        a1.x += g.x; a1.y += g.y; a1.z += g.z; a1.w += g.w;
    }
    // final 0..3 edges: only the first (e-i) groups load
    if (grp < e - i) {
        int c = col[i + grp];
        float4 g = h4_to_f4(*(const float2*)(Gf + (size_t)c * EMB));
        a2.x += g.x; a2.y += g.y; a2.z += g.z; a2.w += g.w;
    }

    float4 r;
    r.x = (a0.x + a1.x) + (a2.x + a3.x);
    r.y = (a0.y + a1.y) + (a2.y + a3.y);
    r.z = (a0.z + a1.z) + (a2.z + a3.z);
    r.w = (a0.w + a1.w) + (a2.w + a3.w);
    // combine the 4 sixteen-lane groups
    r.x += __shfl_xor(r.x, 16, 64);
    r.y += __shfl_xor(r.y, 16, 64);
    r.z += __shfl_xor(r.z, 16, 64);
    r.w += __shfl_xor(r.w, 16, 64);
    r.x += __shfl_xor(r.x, 32, 64);
    r.y += __shfl_xor(r.y, 32, 64);
    r.z += __shfl_xor(r.z, 32, 64);
    r.w += __shfl_xor(r.w, 32, 64);
    return r;   // all 64 lanes: full sum for features [4*f4 .. 4*f4+3]
}

__global__ __launch_bounds__(256) void agg_k(
    const __half* __restrict__ G, const float* __restrict__ dinv,
    const int* __restrict__ rowptr, const int* __restrict__ col,
    const float* __restrict__ bias, float* __restrict__ Hout, int N) {
    int gw = (blockIdx.x * 256 + threadIdx.x) >> 6;
    int lane = threadIdx.x & 63;
    if (gw >= N) return;
    int grp = lane >> 4;
    int f4 = lane & 15;
    int s = rowptr[gw], e = rowptr[gw + 1];
    float4 r = agg_node4(G, col, s, e, gw, grp, f4);
    float d = dinv[gw];
    float4 bv = *(const float4*)(bias + f4 * 4);
    float4 val = make_float4(r.x * d + bv.x, r.y * d + bv.y,
                             r.z * d + bv.z, r.w * d + bv.w);
    if (grp == 0)
        *(float4*)(Hout + (size_t)gw * EMB + f4 * 4) = val;
}

// Final layer: also project y @ Wout + bout into Out.
__global__ __launch_bounds__(256) void agg_final_k(
    const __half* __restrict__ G, const float* __restrict__ dinv,
    const int* __restrict__ rowptr, const int* __restrict__ col,
    const float* __restrict__ bias, const float* __restrict__ Wout,
    const float* __restrict__ bout, float* __restrict__ Y,
    float* __restrict__ Out, int N) {
    int gw = (blockIdx.x * 256 + threadIdx.x) >> 6;
    int lane = threadIdx.x & 63;
    if (gw >= N) return;
    int grp = lane >> 4;
    int f4 = lane & 15;
    int s = rowptr[gw], e = rowptr[gw + 1];
    float4 r = agg_node4(G, col, s, e, gw, grp, f4);
    float d = dinv[gw];
    float4 bv = *(const float4*)(bias + f4 * 4);
    float4 val = make_float4(r.x * d + bv.x, r.y * d + bv.y,
                             r.z * d + bv.z, r.w * d + bv.w);
    if (grp == 0)
        *(float4*)(Y + (size_t)gw * EMB + f4 * 4) = val;
    // output projection: every lane holds the same val for its f4 slice;
    // lanes 0..15 together cover all 64 features -> reduce within group.
    float4 wv = *(const float4*)(Wout + f4 * 4);
    float p = val.x * wv.x + val.y * wv.y + val.z * wv.z + val.w * wv.w;
    p += __shfl_xor(p, 8, 64);
    p += __shfl_xor(p, 4, 64);
    p += __shfl_xor(p, 2, 64);
    p += __shfl_xor(p, 1, 64);
    if (lane == 0) Out[gw] = p + bout[0];
}

// ---------------- launch ----------------

extern "C" void kernel_launch(void* const* d_in, const int* in_sizes, int n_in,
                              void* d_out, int out_size, void* d_ws, size_t ws_size,
                              hipStream_t stream) {
    const float* x    = (const float*)d_in[0];
    const int*   ei   = (const int*)d_in[1];
    const float* W0   = (const float*)d_in[3];
    const float* b0   = (const float*)d_in[4];
    const float* W1   = (const float*)d_in[5];
    const float* b1   = (const float*)d_in[6];
    const float* W2   = (const float*)d_in[7];
    const float* b2   = (const float*)d_in[8];
    const float* W3   = (const float*)d_in[9];
    const float* b3   = (const float*)d_in[10];
    const float* Wout = (const float*)d_in[11];
    const float* bout = (const float*)d_in[12];

    const int N = in_sizes[0] / FEAT;      // 100000
    const int E = in_sizes[1] / 2;         // 3200000
    const int* srcp = ei;                  // edge_index[0]
    const int* dstp = ei + E;              // edge_index[1]
    const int nbin = (N + BINSIZE - 1) / BINSIZE;   // 391

    // workspace layout (regions padded to 64 elems for float4 alignment)
    const int NP = ((N + 64) + 63) / 64 * 64;   // holds N+1
    float* dinv  = (float*)d_ws;
    int* rowptr  = (int*)(dinv + NP);
    int* bincnt  = rowptr + NP;
    int* binptr  = bincnt + 1024;
    int* bincur  = binptr + 1024;
    int* col     = bincur + 1024;
    float* bufA  = (float*)(col + ((E + 63) / 64) * 64);
    int* ebuf    = (int*)bufA;            // aliased: ebuf dead before first gemm
    __half* Gbuf = (__half*)bufA;         // fp16 G (12.8MB) also aliases here

    float* Out = (float*)d_out;
    float* Y   = Out + N;                 // reuse y-region of d_out as ping-pong buffer

    const int gemm_blocks = (N + 63) / 64;
    const int agg_blocks  = (N + 3) / 4;
    const int nchunk = (E + CHUNK - 1) / CHUNK;

    // --- CSR build ---
    zero_k<<<1, 1024, 0, stream>>>(bincnt, 1024);
    bin_count_k<<<nchunk, 256, 0, stream>>>(dstp, bincnt, E);
    binscan_k<<<1, 512, 0, stream>>>(bincnt, binptr, bincur, nbin, E);
    bin_edges_k<<<nchunk, 256, 0, stream>>>(srcp, dstp, bincur, ebuf, E);
    build_csr_k<<<nbin, 256, 0, stream>>>(ebuf, binptr, rowptr, dinv, col, N, E, nbin);

    // --- layer 0 (K=128) ---
    gemm_scale_k<FEAT><<<gemm_blocks, 256, 0, stream>>>(x, W0, dinv, Gbuf, N);
    agg_k<<<agg_blocks, 256, 0, stream>>>(Gbuf, dinv, rowptr, col, b0, Y, N);
    // --- layer 1 ---
    gemm_scale_k<EMB><<<gemm_blocks, 256, 0, stream>>>(Y, W1, dinv, Gbuf, N);
    agg_k<<<agg_blocks, 256, 0, stream>>>(Gbuf, dinv, rowptr, col, b1, Y, N);
    // --- layer 2 ---
    gemm_scale_k<EMB><<<gemm_blocks, 256, 0, stream>>>(Y, W2, dinv, Gbuf, N);
    agg_k<<<agg_blocks, 256, 0, stream>>>(Gbuf, dinv, rowptr, col, b2, Y, N);
    // --- layer 3 + output projection ---
    gemm_scale_k<EMB><<<gemm_blocks, 256, 0, stream>>>(Y, W3, dinv, Gbuf, N);
    agg_final_k<<<agg_blocks, 256, 0, stream>>>(Gbuf, dinv, rowptr, col, b3, Wout, bout,
                                                Y, Out, N);
}

// Round 3
// 579.291 us; speedup vs baseline: 1.2929x; 1.0134x over previous
//
#include <hip/hip_runtime.h>
#include <hip/hip_fp16.h>

// ---------------------------------------------------------------------------
// GCN: 4 layers of  h' = A_hat_norm (h @ W) + b   on fixed graph, fp32.
// deg[i] = in_degree(i) + 1 (self loop), dinv = 1/sqrt(deg),
// g = (h@W) * dinv[row]  (GEMM epilogue), then per-dst:
//   h'[dst] = dinv[dst] * ( g[dst] + sum_{src in N(dst)} g[src] ) + b
// R3: CSR fill via binned counting sort (L2-merged scatters).
// R4: per-node degree/scan/fill in LDS per 256-node bin. (784us)
// R9: agg gather unrolled to 8 chains. (748us)
// R10: dwordx4 gathers, 16 rows in flight/wave. (749us) -> fp32 agg was
//   miss-path BW-bound (FETCH 362MB pinned at 3.7TB/s).
// R11: fp16 G. FETCH 161MB, agg 71us, total 587us. absmax unchanged.
//   Post: nothing saturated now (HBM 33%, VALU 47%, occ 72%) -> agg is
//   latency/queuing-bound, NOT at a BW ceiling. Deeper MLP should pay now
//   (it couldn't in R10 because the miss path was pinned).
// R12: 8-lane row slices (dwordx4 of fp16): one load instr = 8 rows,
//   4 chains = 32 rows in flight/wave (2x R11) at half the instr count.
//   col[] stores BYTE offsets (src<<7) -> SGPR-base+voffset addressing.
//   readfirstlane(gw) scalarizes rowptr/dinv loads. zero_k -> memsetAsync.
//   Predict: agg 71->~55us, FETCH unchanged, total ~520-540us. If agg
//   unchanged: 128B-random miss path ceiling established -> pivot to
//   non-agg 300us next.
// ---------------------------------------------------------------------------

#define FEAT 128
#define EMB 64
#define BINSHIFT 8
#define BINSIZE 256
#define NBIN 391          // ceil(100000/256)
#define CHUNK 8192

// ---------------- CSR build ----------------

// Pass A: per-bin edge counts. LDS histogram per chunk.
__global__ __launch_bounds__(256) void bin_count_k(
    const int* __restrict__ dst, int* __restrict__ bincnt, int E) {
    __shared__ int hist[NBIN];
    int t = threadIdx.x;
    int base = blockIdx.x * CHUNK;
    int end = min(base + CHUNK, E);
    for (int i = t; i < NBIN; i += 256) hist[i] = 0;
    __syncthreads();
    for (int e = base + t; e < end; e += 256)
        atomicAdd(&hist[dst[e] >> BINSHIFT], 1);
    __syncthreads();
    for (int b = t; b < NBIN; b += 256) {
        int c = hist[b];
        if (c > 0) atomicAdd(&bincnt[b], c);
    }
}

// exclusive scan of bin counts (NBIN <= 512), writes binptr + bincur.
__global__ void binscan_k(const int* __restrict__ bincnt, int* __restrict__ binptr,
                          int* __restrict__ bincur, int nbin, int E) {
    __shared__ int s[512];
    int t = threadIdx.x;
    int v = (t < nbin) ? bincnt[t] : 0;
    s[t] = v;
    __syncthreads();
    for (int off = 1; off < 512; off <<= 1) {
        int tv = (t >= off) ? s[t - off] : 0;
        __syncthreads();
        s[t] += tv;
        __syncthreads();
    }
    if (t < nbin) {
        int excl = s[t] - v;
        binptr[t] = excl;
        bincur[t] = excl;
    }
    if (t == 0) binptr[nbin] = E;
}

// Pass B: scatter edges into dst-range bins. One block per 8192-edge chunk.
// Output word: src | (dst&255)<<24  (src < 2^17 fits in 24 bits).
__global__ __launch_bounds__(256) void bin_edges_k(
    const int* __restrict__ src, const int* __restrict__ dst,
    int* __restrict__ bincur, int* __restrict__ ebuf, int E) {
    __shared__ int hist[NBIN];
    __shared__ int lcur[NBIN];
    int t = threadIdx.x;
    int base = blockIdx.x * CHUNK;
    int end = min(base + CHUNK, E);
    for (int i = t; i < NBIN; i += 256) hist[i] = 0;
    __syncthreads();
    for (int e = base + t; e < end; e += 256)
        atomicAdd(&hist[dst[e] >> BINSHIFT], 1);
    __syncthreads();
    for (int b = t; b < NBIN; b += 256) {
        int c = hist[b];
        lcur[b] = (c > 0) ? atomicAdd(&bincur[b], c) : 0;
    }
    __syncthreads();
    for (int e = base + t; e < end; e += 256) {
        int d = dst[e];
        int bin = d >> BINSHIFT;
        int r = atomicAdd(&lcur[bin], 1);
        ebuf[r] = src[e] | ((d & (BINSIZE - 1)) << 24);
    }
}

// Pass C: one block per bin. LDS degree count -> LDS scan -> rowptr/dinv
// writes -> col scatter with LDS cursors. col stores BYTE offsets (src*128).
__global__ __launch_bounds__(256) void build_csr_k(
    const int* __restrict__ ebuf, const int* __restrict__ binptr,
    int* __restrict__ rowptr, float* __restrict__ dinv,
    int* __restrict__ col, int N, int E, int nbin) {
    __shared__ int lcnt[BINSIZE];
    __shared__ int lscan[BINSIZE];
    __shared__ int lcur[BINSIZE];
    int b = blockIdx.x;
    int t = threadIdx.x;
    int n0 = b << BINSHIFT;
    int e0 = binptr[b];
    int e1 = binptr[b + 1];

    lcnt[t] = 0;
    __syncthreads();
    for (int i = e0 + t; i < e1; i += 256)
        atomicAdd(&lcnt[((unsigned)ebuf[i]) >> 24], 1);
    __syncthreads();

    int v = lcnt[t];
    lscan[t] = v;
    __syncthreads();
    for (int off = 1; off < 256; off <<= 1) {
        int tv = (t >= off) ? lscan[t - off] : 0;
        __syncthreads();
        lscan[t] += tv;
        __syncthreads();
    }
    int excl = e0 + lscan[t] - v;
    lcur[t] = excl;
    if (n0 + t < N) {
        rowptr[n0 + t] = excl;
        dinv[n0 + t] = 1.0f / sqrtf((float)(v + 1));
    }
    if (b == nbin - 1 && t == 0) rowptr[N] = E;
    __syncthreads();

    for (int i = e0 + t; i < e1; i += 256) {
        int w = ebuf[i];
        int dl = ((unsigned)w) >> 24;
        int p = atomicAdd(&lcur[dl], 1);
        col[p] = (w & 0xFFFFFF) << 7;   // byte offset into fp16 G (row = 128B)
    }
}

// ---------------- GEMM + dinv row-scale:  G = (H @ W) * dinv[row], fp16 out ----
// Block: 256 threads -> 64 rows x 64 cols, each thread 4x4 outputs.
// Manual 1-deep pipeline on the A loads; unroll 1 keeps VGPR < 128.
template <int K>
__global__ __launch_bounds__(256, 4) void gemm_scale_k(
    const float* __restrict__ H, const float* __restrict__ W,
    const float* __restrict__ dinv, __half* __restrict__ G, int N) {
    __shared__ float Ws[K * EMB];
    int t = threadIdx.x;
    for (int i = t * 4; i < K * EMB; i += 1024) {
        *(float4*)(Ws + i) = *(const float4*)(W + i);
    }
    __syncthreads();

    int tc = t & 15;   // col group -> 4 cols
    int tr = t >> 4;   // row group -> 4 rows
    int j0 = tc * 4;
    int r0 = blockIdx.x * 64 + tr * 4;
    if (r0 >= N) return;

    const float* hp[4];
#pragma unroll
    for (int i = 0; i < 4; i++) {
        int r = (r0 + i < N) ? (r0 + i) : (N - 1);
        hp[i] = H + (size_t)r * K;
    }

    float acc[4][4] = {{0.f}};
    float4 a[4], an[4];
#pragma unroll
    for (int i = 0; i < 4; i++) a[i] = *(const float4*)(hp[i]);

#pragma unroll 1
    for (int k = 0; k < K; k += 4) {
        if (k + 4 < K) {
#pragma unroll
            for (int i = 0; i < 4; i++) an[i] = *(const float4*)(hp[i] + k + 4);
        }
#pragma unroll
        for (int kk = 0; kk < 4; kk++) {
            float4 wv = *(const float4*)(Ws + (k + kk) * EMB + j0);
#pragma unroll
            for (int i = 0; i < 4; i++) {
                float av = (kk == 0) ? a[i].x : (kk == 1) ? a[i].y : (kk == 2) ? a[i].z : a[i].w;
                acc[i][0] = fmaf(av, wv.x, acc[i][0]);
                acc[i][1] = fmaf(av, wv.y, acc[i][1]);
                acc[i][2] = fmaf(av, wv.z, acc[i][2]);
                acc[i][3] = fmaf(av, wv.w, acc[i][3]);
            }
        }
#pragma unroll
        for (int i = 0; i < 4; i++) a[i] = an[i];
    }

#pragma unroll
    for (int i = 0; i < 4; i++) {
        if (r0 + i < N) {
            float s = dinv[r0 + i];
            union { __half2 h2[2]; float2 f2; } o;
            o.h2[0] = __floats2half2_rn(acc[i][0] * s, acc[i][1] * s);
            o.h2[1] = __floats2half2_rn(acc[i][2] * s, acc[i][3] * s);
            *(float2*)(G + (size_t)(r0 + i) * EMB + j0) = o.f2;
        }
    }
}

// ---------------- Aggregation: one wave per node, fp16 G rows ----------------
// R12: 8 lanes cover one 128B fp16 G-row (dwordx4 = 8 halves per lane); the
// wave's 8 eight-lane groups each handle every 8th edge -> one load
// instruction fetches 8 rows. 4 chains -> 32 rows outstanding per wave.
// col[] holds byte offsets; col values prefetched one iteration ahead.
// Accumulate fp32; epilogue combines the 8 groups with shfl_xor(8,16,32).

__device__ __forceinline__ void h8_acc(float (&a)[8], float4 raw) {
    union { float4 f4; __half2 h2[4]; } u;
    u.f4 = raw;
    float2 p0 = __half22float2(u.h2[0]);
    float2 p1 = __half22float2(u.h2[1]);
    float2 p2 = __half22float2(u.h2[2]);
    float2 p3 = __half22float2(u.h2[3]);
    a[0] += p0.x; a[1] += p0.y; a[2] += p1.x; a[3] += p1.y;
    a[4] += p2.x; a[5] += p2.y; a[6] += p3.x; a[7] += p3.y;
}

__device__ __forceinline__ void agg_node8(const __half* __restrict__ G,
                                          const int* __restrict__ coff,
                                          int s, int e, int selfoff,
                                          int grp, int f8, float (&r)[8]) {
    const char* Gb = (const char*)G + f8 * 16;   // lane's 16B slice in a row
    float a0[8] = {0.f, 0.f, 0.f, 0.f, 0.f, 0.f, 0.f, 0.f};
    float a1[8] = {0.f, 0.f, 0.f, 0.f, 0.f, 0.f, 0.f, 0.f};
    float a2[8] = {0.f, 0.f, 0.f, 0.f, 0.f, 0.f, 0.f, 0.f};
    float a3[8] = {0.f, 0.f, 0.f, 0.f, 0.f, 0.f, 0.f, 0.f};
    if (grp == 0) h8_acc(a0, *(const float4*)(Gb + selfoff));  // self loop

    int i = s;
    if (i + 32 <= e) {
        int c0 = coff[i + grp];
        int c1 = coff[i + 8 + grp];
        int c2 = coff[i + 16 + grp];
        int c3 = coff[i + 24 + grp];
        while (true) {
            float4 g0 = *(const float4*)(Gb + (size_t)(unsigned)c0);
            float4 g1 = *(const float4*)(Gb + (size_t)(unsigned)c1);
            float4 g2 = *(const float4*)(Gb + (size_t)(unsigned)c2);
            float4 g3 = *(const float4*)(Gb + (size_t)(unsigned)c3);
            i += 32;
            bool more = (i + 32 <= e);
            if (more) {                       // prefetch next iter's offsets
                c0 = coff[i + grp];
                c1 = coff[i + 8 + grp];
                c2 = coff[i + 16 + grp];
                c3 = coff[i + 24 + grp];
            }
            h8_acc(a0, g0);
            h8_acc(a1, g1);
            h8_acc(a2, g2);
            h8_acc(a3, g3);
            if (!more) break;
        }
    }
    // 8..31 leftover edges, 8 at a time (one row per group)
    for (; i + 8 <= e; i += 8) {
        float4 g = *(const float4*)(Gb + (size_t)(unsigned)coff[i + grp]);
        h8_acc(a1, g);
    }
    // final 0..7 edges: only the first (e-i) groups load
    if (grp < e - i) {
        float4 g = *(const float4*)(Gb + (size_t)(unsigned)coff[i + grp]);
        h8_acc(a2, g);
    }

#pragma unroll
    for (int k = 0; k < 8; k++) {
        float v = (a0[k] + a1[k]) + (a2[k] + a3[k]);
        v += __shfl_xor(v, 8, 64);
        v += __shfl_xor(v, 16, 64);
        v += __shfl_xor(v, 32, 64);
        r[k] = v;   // all 64 lanes: full sum for features [8*f8 .. 8*f8+7]
    }
}

__global__ __launch_bounds__(256) void agg_k(
    const __half* __restrict__ G, const float* __restrict__ dinv,
    const int* __restrict__ rowptr, const int* __restrict__ coff,
    const float* __restrict__ bias, float* __restrict__ Hout, int N) {
    int gw = (blockIdx.x * 256 + threadIdx.x) >> 6;
    int lane = threadIdx.x & 63;
    if (gw >= N) return;
    gw = __builtin_amdgcn_readfirstlane(gw);    // wave-uniform -> scalar loads
    int grp = lane >> 3;
    int f8 = lane & 7;
    int s = rowptr[gw], e = rowptr[gw + 1];
    float r[8];
    agg_node8(G, coff, s, e, gw << 7, grp, f8, r);
    if (grp == 0) {
        float d = dinv[gw];
        float4 b0v = *(const float4*)(bias + f8 * 8);
        float4 b1v = *(const float4*)(bias + f8 * 8 + 4);
        float4 lo = make_float4(r[0] * d + b0v.x, r[1] * d + b0v.y,
                                r[2] * d + b0v.z, r[3] * d + b0v.w);
        float4 hi = make_float4(r[4] * d + b1v.x, r[5] * d + b1v.y,
                                r[6] * d + b1v.z, r[7] * d + b1v.w);
        float* o = Hout + (size_t)gw * EMB + f8 * 8;
        *(float4*)o = lo;
        *(float4*)(o + 4) = hi;
    }
}

// Final layer: also project y @ Wout + bout into Out.
__global__ __launch_bounds__(256) void agg_final_k(
    const __half* __restrict__ G, const float* __restrict__ dinv,
    const int* __restrict__ rowptr, const int* __restrict__ coff,
    const float* __restrict__ bias, const float* __restrict__ Wout,
    const float* __restrict__ bout, float* __restrict__ Y,
    float* __restrict__ Out, int N) {
    int gw = (blockIdx.x * 256 + threadIdx.x) >> 6;
    int lane = threadIdx.x & 63;
    if (gw >= N) return;
    gw = __builtin_amdgcn_readfirstlane(gw);
    int grp = lane >> 3;
    int f8 = lane & 7;
    int s = rowptr[gw], e = rowptr[gw + 1];
    float r[8];
    agg_node8(G, coff, s, e, gw << 7, grp, f8, r);
    float d = dinv[gw];
    float4 b0v = *(const float4*)(bias + f8 * 8);
    float4 b1v = *(const float4*)(bias + f8 * 8 + 4);
    float v0 = r[0] * d + b0v.x, v1 = r[1] * d + b0v.y;
    float v2 = r[2] * d + b0v.z, v3 = r[3] * d + b0v.w;
    float v4 = r[4] * d + b1v.x, v5 = r[5] * d + b1v.y;
    float v6 = r[6] * d + b1v.z, v7 = r[7] * d + b1v.w;
    if (grp == 0) {
        float* o = Y + (size_t)gw * EMB + f8 * 8;
        *(float4*)o = make_float4(v0, v1, v2, v3);
        *(float4*)(o + 4) = make_float4(v4, v5, v6, v7);
    }
    // output projection: each lane holds 8 features; lanes 0..7 cover all 64.
    float4 w0v = *(const float4*)(Wout + f8 * 8);
    float4 w1v = *(const float4*)(Wout + f8 * 8 + 4);
    float p = v0 * w0v.x + v1 * w0v.y + v2 * w0v.z + v3 * w0v.w +
              v4 * w1v.x + v5 * w1v.y + v6 * w1v.z + v7 * w1v.w;
    p += __shfl_xor(p, 1, 8);
    p += __shfl_xor(p, 2, 8);
    p += __shfl_xor(p, 4, 8);
    if (lane == 0) Out[gw] = p + bout[0];
}

// ---------------- launch ----------------

extern "C" void kernel_launch(void* const* d_in, const int* in_sizes, int n_in,
                              void* d_out, int out_size, void* d_ws, size_t ws_size,
                              hipStream_t stream) {
    const float* x    = (const float*)d_in[0];
    const int*   ei   = (const int*)d_in[1];
    const float* W0   = (const float*)d_in[3];
    const float* b0   = (const float*)d_in[4];
    const float* W1   = (const float*)d_in[5];
    const float* b1   = (const float*)d_in[6];
    const float* W2   = (const float*)d_in[7];
    const float* b2   = (const float*)d_in[8];
    const float* W3   = (const float*)d_in[9];
    const float* b3   = (const float*)d_in[10];
    const float* Wout = (const float*)d_in[11];
    const float* bout = (const float*)d_in[12];

    const int N = in_sizes[0] / FEAT;      // 100000
    const int E = in_sizes[1] / 2;         // 3200000
    const int* srcp = ei;                  // edge_index[0]
    const int* dstp = ei + E;              // edge_index[1]
    const int nbin = (N + BINSIZE - 1) / BINSIZE;   // 391

    // workspace layout (regions padded to 64 elems for float4 alignment)
    const int NP = ((N + 64) + 63) / 64 * 64;   // holds N+1
    float* dinv  = (float*)d_ws;
    int* rowptr  = (int*)(dinv + NP);
    int* bincnt  = rowptr + NP;
    int* binptr  = bincnt + 1024;
    int* bincur  = binptr + 1024;
    int* col     = bincur + 1024;
    float* bufA  = (float*)(col + ((E + 63) / 64) * 64);
    int* ebuf    = (int*)bufA;            // aliased: ebuf dead before first gemm
    __half* Gbuf = (__half*)bufA;         // fp16 G (12.8MB) also aliases here

    float* Out = (float*)d_out;
    float* Y   = Out + N;                 // reuse y-region of d_out as ping-pong buffer

    const int gemm_blocks = (N + 63) / 64;
    const int agg_blocks  = (N + 3) / 4;
    const int nchunk = (E + CHUNK - 1) / CHUNK;

    // --- CSR build ---
    hipMemsetAsync(bincnt, 0, 1024 * sizeof(int), stream);
    bin_count_k<<<nchunk, 256, 0, stream>>>(dstp, bincnt, E);
    binscan_k<<<1, 512, 0, stream>>>(bincnt, binptr, bincur, nbin, E);
    bin_edges_k<<<nchunk, 256, 0, stream>>>(srcp, dstp, bincur, ebuf, E);
    build_csr_k<<<nbin, 256, 0, stream>>>(ebuf, binptr, rowptr, dinv, col, N, E, nbin);

    // --- layer 0 (K=128) ---
    gemm_scale_k<FEAT><<<gemm_blocks, 256, 0, stream>>>(x, W0, dinv, Gbuf, N);
    agg_k<<<agg_blocks, 256, 0, stream>>>(Gbuf, dinv, rowptr, col, b0, Y, N);
    // --- layer 1 ---
    gemm_scale_k<EMB><<<gemm_blocks, 256, 0, stream>>>(Y, W1, dinv, Gbuf, N);
    agg_k<<<agg_blocks, 256, 0, stream>>>(Gbuf, dinv, rowptr, col, b1, Y, N);
    // --- layer 2 ---
    gemm_scale_k<EMB><<<gemm_blocks, 256, 0, stream>>>(Y, W2, dinv, Gbuf, N);
    agg_k<<<agg_blocks, 256, 0, stream>>>(Gbuf, dinv, rowptr, col, b2, Y, N);
    // --- layer 3 + output projection ---
    gemm_scale_k<EMB><<<gemm_blocks, 256, 0, stream>>>(Y, W3, dinv, Gbuf, N);
    agg_final_k<<<agg_blocks, 256, 0, stream>>>(Gbuf, dinv, rowptr, col, b3, Wout, bout,
                                                Y, Out, N);
}